// Round 15
// baseline (185.256 us; speedup 1.0000x reference)
//
#include <hip/hip_runtime.h>

// Lennard-Jones — R15: phase ablation INSIDE the fused kernel + merged accum.
// R13/R14 eliminated occupancy/lookup-source/reservation-atomics/write-coalescing
// as causes of the fused kernel's ~28us overhead. V1/V2 shadow probes (x3 reps,
// asm-kept-live) decompose {front+hist+scan+reserve} vs {+rank} vs {+copyout}.
// Real change: accum+reduce merged -> accum_direct writes out (-1 dispatch).
//
// Inputs: 0 sigma[16,16] 1 delta[16,16] 2 epsilon[16,16] (f32)
//         3 edge_len[E] 4 edge_cutoff[E] (f32)  5 edge_index[2,E] (int32)
//         6 atom_types[N] (int32)         Output: [N,1] f32.

#define THREADS  512
#define EPT      8
#define EPB      (THREADS*EPT)   // 4096
#define STHREADS 256
#define BSHIFT   9
#define BSIZE    512
#define MAXB2    256
#define NMASK    511u
#define LDSWORDS 12544
#define PROBE_REPS 3

__device__ __forceinline__ float lj_energy(float sig, float dlt, float eps,
                                           float len, float cut) {
    const float r  = sig / (len - dlt);
    const float r2 = r * r;
    const float x  = r2 * r2 * r2;               // (sig/(len-dlt))^6
    return 2.0f * eps * (x * x - x) * cut;
}

__device__ __forceinline__ void load_params(const float* __restrict__ sigma,
                                            const float* __restrict__ delta,
                                            const float* __restrict__ epsilon,
                                            float* s_sig, float* s_dlt, float* s_eps,
                                            int t) {
    if (t < 256) {
        const int i  = t >> 4;
        const int j  = t & 15;
        const int lo = min(i, j);
        const int hi = max(i, j);
        const int src = lo * 16 + hi;        // sym = triu(p)+triu(p,1).T
        s_sig[t] = fmaxf(sigma[src],   0.0f);
        s_dlt[t] = fmaxf(delta[src],   0.0f);
        s_eps[t] = fmaxf(epsilon[src], 0.0f);
    }
}

// ---------------- K0: pack atom_types into nibbles + zero 3 cursor sets -------
__global__ __launch_bounds__(STHREADS) void pack_types_kernel(
    const int* __restrict__ at, uint32_t* __restrict__ packed,
    uint32_t* __restrict__ gcursor, int n_nodes)
{
    if (blockIdx.x == 0) {
        gcursor[threadIdx.x]       = 0u;     // real
        gcursor[threadIdx.x + 256] = 0u;     // probe V1
        gcursor[threadIdx.x + 512] = 0u;     // probe V2
    }
    const int w = blockIdx.x * STHREADS + threadIdx.x;
    const int nwords = (n_nodes + 7) >> 3;
    if (w >= nwords) return;
    const int base = w * 8;
    uint32_t v = 0;
    if (base + 8 <= n_nodes) {
        const int4 a = *reinterpret_cast<const int4*>(at + base);
        const int4 b = *reinterpret_cast<const int4*>(at + base + 4);
        v =  (uint32_t)(a.x & 15)        | ((uint32_t)(a.y & 15) << 4)
          | ((uint32_t)(a.z & 15) << 8)  | ((uint32_t)(a.w & 15) << 12)
          | ((uint32_t)(b.x & 15) << 16) | ((uint32_t)(b.y & 15) << 20)
          | ((uint32_t)(b.z & 15) << 24) | ((uint32_t)(b.w & 15) << 28);
    } else {
        for (int k = 0; k < 8; ++k) {
            const int idx = base + k;
            const uint32_t tv = (idx < n_nodes) ? (uint32_t)(at[idx] & 15) : 0u;
            v |= tv << (4 * k);
        }
    }
    packed[w] = v;
}

// ---------------- K1: fused kernel, templated phase ablation ------------------
// V=0: full (real).  V=1: front+hist+scan+reserve only.  V=2: +rank, no copyout.
// V!=0 run PROBE_REPS inner reps with asm-opaqued addresses.
template<int V>
__global__ __launch_bounds__(THREADS) void lj_fused_t(
    const float* __restrict__ sigma,
    const float* __restrict__ delta,
    const float* __restrict__ epsilon,
    const float* __restrict__ edge_len,
    const float* __restrict__ edge_cutoff,
    const int*  __restrict__ edge_index,
    const uint32_t* __restrict__ packedT,
    uint32_t* __restrict__ gcursor,          // per-variant cursor set
    uint32_t* __restrict__ pairs,
    int n_edges, int n_nodes, int nbucket, int REG)
{
    __shared__ float s_sig[256], s_dlt[256], s_eps[256];
    __shared__ __align__(16) uint32_t typeT[LDSWORDS];
    __shared__ uint32_t hist[MAXB2];
    __shared__ uint32_t lbase[MAXB2];
    __shared__ uint32_t gbase[MAXB2];
    __shared__ uint32_t stage[EPB];

    const int t = threadIdx.x;
    load_params(sigma, delta, epsilon, s_sig, s_dlt, s_eps, t);

    const int nwords = (n_nodes + 7) >> 3;
    {
        const int nw4 = nwords >> 2;
        const uint4* s4 = reinterpret_cast<const uint4*>(packedT);
        uint4* d4 = reinterpret_cast<uint4*>(typeT);
        for (int i = t; i < nw4; i += THREADS) d4[i] = s4[i];
        for (int i = (nw4 << 2) + t; i < nwords; i += THREADS) typeT[i] = packedT[i];
    }

    #define TYPE_OF(idx) ((typeT[(idx) >> 3] >> (((idx) & 7) << 2)) & 15u)

    const int blk     = blockIdx.x;
    const int blkbase = blk * EPB;
    const int nval    = min(EPB, n_edges - blkbase);

    const int NREP = (V == 0) ? 1 : PROBE_REPS;
    for (int rep = 0; rep < NREP; ++rep) {
        // clear hist (counts) each rep
        if (t < MAXB2) hist[t] = 0u;
        __syncthreads();

        // ---- front-end: stream + lookup + energy + pack + histogram ----
        uint32_t pk[EPT];
        int      bk[EPT];
        #pragma unroll
        for (int i = 0; i < EPT / 4; ++i) {
            int g = blkbase + i * (THREADS * 4) + t * 4;
            if constexpr (V != 0) { asm volatile("" : "+v"(g)); }  // defeat CSE
            if (g + 3 < n_edges) {
                const int4   ctr = *reinterpret_cast<const int4*>(edge_index + g);
                const int4   oth = *reinterpret_cast<const int4*>(edge_index + n_edges + g);
                const float4 len = *reinterpret_cast<const float4*>(edge_len + g);
                const float4 cut = *reinterpret_cast<const float4*>(edge_cutoff + g);
                const int   c[4] = {ctr.x, ctr.y, ctr.z, ctr.w};
                const int   o[4] = {oth.x, oth.y, oth.z, oth.w};
                const float L[4] = {len.x, len.y, len.z, len.w};
                const float C[4] = {cut.x, cut.y, cut.z, cut.w};
                #pragma unroll
                for (int k = 0; k < 4; ++k) {
                    const int fl = (int)((TYPE_OF(c[k]) << 4) | TYPE_OF(o[k]));
                    const float e = lj_energy(s_sig[fl], s_dlt[fl], s_eps[fl],
                                              L[k], C[k]);
                    pk[i*4+k] = (__float_as_uint(e) & ~NMASK) | (uint32_t)(c[k] & NMASK);
                    bk[i*4+k] = c[k] >> BSHIFT;
                    atomicAdd(&hist[bk[i*4+k]], 1u);
                }
            } else {
                #pragma unroll
                for (int k = 0; k < 4; ++k) {
                    const int e_idx = g + k;
                    if (e_idx < n_edges) {
                        const int ci = edge_index[e_idx];
                        const int oi = edge_index[n_edges + e_idx];
                        const int fl = (int)((TYPE_OF(ci) << 4) | TYPE_OF(oi));
                        const float e = lj_energy(s_sig[fl], s_dlt[fl], s_eps[fl],
                                                  edge_len[e_idx], edge_cutoff[e_idx]);
                        pk[i*4+k] = (__float_as_uint(e) & ~NMASK) | (uint32_t)(ci & NMASK);
                        bk[i*4+k] = ci >> BSHIFT;
                        atomicAdd(&hist[bk[i*4+k]], 1u);
                    } else {
                        bk[i*4+k] = -1;
                    }
                }
            }
        }
        __syncthreads();

        // ---- wave-0 scan -> lbase + cursor ----
        if (t < 64) {
            uint32_t v[4]; uint32_t s = 0;
            #pragma unroll
            for (int k = 0; k < 4; ++k) {
                const uint32_t tmp = hist[t * 4 + k];
                v[k] = s; s += tmp;
            }
            uint32_t inc = s;
            #pragma unroll
            for (int off = 1; off < 64; off <<= 1) {
                const uint32_t u = __shfl_up(inc, off, 64);
                if (t >= off) inc += u;
            }
            const uint32_t lane_excl = inc - s;
            #pragma unroll
            for (int k = 0; k < 4; ++k) {
                const uint32_t e = lane_excl + v[k];
                lbase[t * 4 + k] = e;
                hist[t * 4 + k]  = e;
            }
        }
        __syncthreads();

        // ---- reserve region slots (u64 bucket-pair atomics) ----
        if (t < MAXB2 / 2) {
            const int b0 = 2 * t, b1 = 2 * t + 1;
            const uint32_t l0 = lbase[b0];
            const uint32_t l1 = lbase[b1];
            const uint32_t l2 = (b1 + 1 < MAXB2) ? lbase[b1 + 1] : (uint32_t)nval;
            const uint32_t cnt0 = l1 - l0;
            const uint32_t cnt1 = l2 - l1;
            if ((cnt0 | cnt1) != 0u) {
                unsigned long long* g64 =
                    reinterpret_cast<unsigned long long*>(gcursor) + t;
                const unsigned long long add =
                    (unsigned long long)cnt0 | ((unsigned long long)cnt1 << 32);
                const unsigned long long old = atomicAdd(g64, add);
                gbase[b0] = (uint32_t)old;
                gbase[b1] = (uint32_t)(old >> 32);
            }
        }

        if constexpr (V == 1) {
            // keep energies live; no rank, no copy-out
            #pragma unroll
            for (int j = 0; j < EPT; ++j) asm volatile("" :: "v"(pk[j]));
            __syncthreads();
            continue;
        }

        // ---- rank-scatter into LDS stage ----
        #pragma unroll
        for (int j = 0; j < EPT; ++j) {
            if (bk[j] >= 0) {
                const uint32_t r = atomicAdd(&hist[bk[j]], 1u);
                stage[r] = pk[j];
            }
        }
        __syncthreads();

        if constexpr (V == 2) {
            // keep stage live; no copy-out
            asm volatile("" :: "v"(stage[(t * 131) & (EPB - 1)]) : "memory");
            __syncthreads();
            continue;
        }

        // ---- run-coalesced copy-out (V==0 only) ----
        const int grp = t >> 3;
        const int lig = t & 7;
        for (int b = grp; b < nbucket; b += 64) {
            const uint32_t l0 = lbase[b];
            const uint32_t l1 = (b + 1 < MAXB2) ? lbase[b + 1] : (uint32_t)nval;
            const uint32_t cnt = l1 - l0;
            const uint32_t base = gbase[b];
            const uint32_t avail = (base < (uint32_t)REG)
                                 ? min(cnt, (uint32_t)REG - base) : 0u;
            uint32_t* dst = pairs + (size_t)b * REG + base;
            for (uint32_t j = lig; j < avail; j += 8)
                dst[j] = stage[l0 + j];
        }
    }
}

// ---------------- K2: direct per-bucket accumulate -> out ---------------------
__global__ __launch_bounds__(THREADS) void lj_accum_direct(
    const uint32_t* __restrict__ pairs,
    const uint32_t* __restrict__ gcursor,
    float* __restrict__ out,
    int REG, int n_nodes)
{
    __shared__ float acc[4][BSIZE];          // 8KB, 4 replicas
    const int t = threadIdx.x;
    const int b = blockIdx.x;

    #pragma unroll
    for (int w = 0; w < 4; ++w) acc[w][t] = 0.0f;
    __syncthreads();

    const int rep = (t >> 6) & 3;
    const uint32_t cnt = min(gcursor[b], (uint32_t)REG);
    const uint32_t* seg = pairs + (size_t)b * REG;
    for (uint32_t i = t; i < cnt; i += THREADS) {
        const uint32_t p = seg[i];
        atomicAdd(&acc[rep][p & NMASK], __uint_as_float(p & ~NMASK));
    }
    __syncthreads();

    const long long n = (long long)b * BSIZE + t;
    if (n < n_nodes)
        out[n] = acc[0][t] + acc[1][t] + acc[2][t] + acc[3][t];
}

// ---------------- fallback: direct device-scope atomics -----------------------
__global__ __launch_bounds__(STHREADS) void lj_scatter_direct(
    const float* __restrict__ sigma,
    const float* __restrict__ delta,
    const float* __restrict__ epsilon,
    const float* __restrict__ edge_len,
    const float* __restrict__ edge_cutoff,
    const int*  __restrict__ edge_index,
    const int*  __restrict__ atom_types,
    float* __restrict__ out,
    int n_edges)
{
    __shared__ float s_sig[256], s_dlt[256], s_eps[256];
    const int t = threadIdx.x;
    load_params(sigma, delta, epsilon, s_sig, s_dlt, s_eps, t);
    __syncthreads();

    const int base = (blockIdx.x * STHREADS + t) * 4;
    if (base >= n_edges) return;
    const int lim = min(base + 4, n_edges);
    for (int e = base; e < lim; ++e) {
        const int ci = edge_index[e];
        const int oi = edge_index[n_edges + e];
        const int fl = (atom_types[ci] << 4) | atom_types[oi];
        const float en = lj_energy(s_sig[fl], s_dlt[fl], s_eps[fl],
                                   edge_len[e], edge_cutoff[e]);
        atomicAdd(out + ci, en);
    }
}

static inline size_t align16(size_t x) { return (x + 15) & ~(size_t)15; }

extern "C" void kernel_launch(void* const* d_in, const int* in_sizes, int n_in,
                              void* d_out, int out_size, void* d_ws, size_t ws_size,
                              hipStream_t stream) {
    const float* sigma       = (const float*)d_in[0];
    const float* delta       = (const float*)d_in[1];
    const float* epsilon     = (const float*)d_in[2];
    const float* edge_len    = (const float*)d_in[3];
    const float* edge_cutoff = (const float*)d_in[4];
    const int*   edge_index  = (const int*)d_in[5];
    const int*   atom_types  = (const int*)d_in[6];
    float*       out         = (float*)d_out;

    const int n_edges = in_sizes[3];
    const int n_nodes = in_sizes[6];

    const int nblk    = (n_edges + EPB - 1) / EPB;
    const int nbucket = (n_nodes + BSIZE - 1) / BSIZE;
    const int nwords  = (n_nodes + 7) >> 3;

    int REG = 2 * (n_edges / (nbucket > 0 ? nbucket : 1));
    REG = ((REG + 1023) / 1024) * 1024;
    if (REG < 2048) REG = 2048;

    const size_t gcur_bytes   = align16(3 * 256 * sizeof(uint32_t));
    const size_t packed_bytes = align16((size_t)nwords * sizeof(uint32_t));
    const size_t pairs_bytes  = align16((size_t)nbucket * REG * sizeof(uint32_t));
    const size_t need = gcur_bytes + packed_bytes + pairs_bytes;

    if (nbucket <= MAXB2 && nwords <= LDSWORDS && ws_size >= need) {
        char* p = (char*)d_ws;
        uint32_t* gcursor = (uint32_t*)p;  p += gcur_bytes;
        uint32_t* packed  = (uint32_t*)p;  p += packed_bytes;
        uint32_t* pairs   = (uint32_t*)p;

        const int pgrid = (nwords + STHREADS - 1) / STHREADS;
        pack_types_kernel<<<pgrid, STHREADS, 0, stream>>>(
            atom_types, packed, gcursor, n_nodes);

        lj_fused_t<0><<<nblk, THREADS, 0, stream>>>(
            sigma, delta, epsilon, edge_len, edge_cutoff,
            edge_index, packed, gcursor, pairs, n_edges, n_nodes, nbucket, REG);

        lj_accum_direct<<<nbucket, THREADS, 0, stream>>>(
            pairs, gcursor, out, REG, n_nodes);

        // ---- shadow ablation probes (write only to their own cursor sets) ----
        lj_fused_t<1><<<nblk, THREADS, 0, stream>>>(
            sigma, delta, epsilon, edge_len, edge_cutoff,
            edge_index, packed, gcursor + 256, pairs, n_edges, n_nodes, nbucket, REG);
        lj_fused_t<2><<<nblk, THREADS, 0, stream>>>(
            sigma, delta, epsilon, edge_len, edge_cutoff,
            edge_index, packed, gcursor + 512, pairs, n_edges, n_nodes, nbucket, REG);
    } else {
        hipMemsetAsync(d_out, 0, (size_t)out_size * sizeof(float), stream);
        const int grid = (n_edges + STHREADS * 4 - 1) / (STHREADS * 4);
        lj_scatter_direct<<<grid, STHREADS, 0, stream>>>(
            sigma, delta, epsilon, edge_len, edge_cutoff,
            edge_index, atom_types, out, n_edges);
    }
}

// Round 16
// 54.358 us; speedup vs baseline: 3.4080x; 3.4080x over previous
//
#include <hip/hip_runtime.h>

// Lennard-Jones per-edge energy + segment-sum — fused binning, replicated cursors.
//
// R15 ablation decode: rank-scatter 0.5us, hist/scan ~1.5us; region-RESERVATION
// ~11us — a per-address serial RMW chain of depth nblk=782 (same depth across
// R11-R14, which is why address-count changes were invariant). R16: 8 cursor
// replica sets (block uses blk&7, bucket regions split into 8 sub-chunks) ->
// chain depth 98, reserve ~1.4us. Accum: one wave per replica-chunk.
//
// Inputs: 0 sigma[16,16] 1 delta[16,16] 2 epsilon[16,16] (f32)
//         3 edge_len[E] 4 edge_cutoff[E] (f32)  5 edge_index[2,E] (int32)
//         6 atom_types[N] (int32)         Output: [N,1] f32.

#define THREADS  512
#define EPT      8
#define EPB      (THREADS*EPT)   // 4096
#define STHREADS 256
#define BSHIFT   9
#define BSIZE    512
#define MAXB2    256
#define NMASK    511u
#define LDSWORDS 12544
#define NREP     8               // cursor/region replica sets

__device__ __forceinline__ float lj_energy(float sig, float dlt, float eps,
                                           float len, float cut) {
    const float r  = sig / (len - dlt);
    const float r2 = r * r;
    const float x  = r2 * r2 * r2;               // (sig/(len-dlt))^6
    return 2.0f * eps * (x * x - x) * cut;
}

__device__ __forceinline__ void load_params(const float* __restrict__ sigma,
                                            const float* __restrict__ delta,
                                            const float* __restrict__ epsilon,
                                            float* s_sig, float* s_dlt, float* s_eps,
                                            int t) {
    if (t < 256) {
        const int i  = t >> 4;
        const int j  = t & 15;
        const int lo = min(i, j);
        const int hi = max(i, j);
        const int src = lo * 16 + hi;        // sym = triu(p)+triu(p,1).T
        s_sig[t] = fmaxf(sigma[src],   0.0f);
        s_dlt[t] = fmaxf(delta[src],   0.0f);
        s_eps[t] = fmaxf(epsilon[src], 0.0f);
    }
}

// ---------------- K0: pack atom_types into nibbles + zero cursor replicas -----
__global__ __launch_bounds__(STHREADS) void pack_types_kernel(
    const int* __restrict__ at, uint32_t* __restrict__ packed,
    uint32_t* __restrict__ gcursor, int n_nodes)
{
    if (blockIdx.x < NREP)
        gcursor[blockIdx.x * 256 + threadIdx.x] = 0u;
    const int w = blockIdx.x * STHREADS + threadIdx.x;
    const int nwords = (n_nodes + 7) >> 3;
    if (w >= nwords) return;
    const int base = w * 8;
    uint32_t v = 0;
    if (base + 8 <= n_nodes) {
        const int4 a = *reinterpret_cast<const int4*>(at + base);
        const int4 b = *reinterpret_cast<const int4*>(at + base + 4);
        v =  (uint32_t)(a.x & 15)        | ((uint32_t)(a.y & 15) << 4)
          | ((uint32_t)(a.z & 15) << 8)  | ((uint32_t)(a.w & 15) << 12)
          | ((uint32_t)(b.x & 15) << 16) | ((uint32_t)(b.y & 15) << 20)
          | ((uint32_t)(b.z & 15) << 24) | ((uint32_t)(b.w & 15) << 28);
    } else {
        for (int k = 0; k < 8; ++k) {
            const int idx = base + k;
            const uint32_t tv = (idx < n_nodes) ? (uint32_t)(at[idx] & 15) : 0u;
            v |= tv << (4 * k);
        }
    }
    packed[w] = v;
}

// ---------------- K1: fused energy + LDS sort + replicated-region scatter -----
__global__ __launch_bounds__(THREADS) void lj_fused(
    const float* __restrict__ sigma,
    const float* __restrict__ delta,
    const float* __restrict__ epsilon,
    const float* __restrict__ edge_len,
    const float* __restrict__ edge_cutoff,
    const int*  __restrict__ edge_index,     // [2,E]
    const uint32_t* __restrict__ packedT,    // [(n+7)/8]
    uint32_t* __restrict__ gcursor,          // [NREP][256] cursors
    uint32_t* __restrict__ pairs,            // [nbucket][NREP][REGr]
    int n_edges, int n_nodes, int nbucket, int REGr)
{
    __shared__ float s_sig[256], s_dlt[256], s_eps[256];
    __shared__ __align__(16) uint32_t typeT[LDSWORDS];  // 50KB nibble table
    __shared__ uint32_t hist[MAXB2];
    __shared__ uint32_t lbase[MAXB2];
    __shared__ uint32_t gbase[MAXB2];
    __shared__ uint32_t stage[EPB];          // 16KB sorted stage

    const int t = threadIdx.x;
    load_params(sigma, delta, epsilon, s_sig, s_dlt, s_eps, t);
    if (t < MAXB2) hist[t] = 0u;

    const int nwords = (n_nodes + 7) >> 3;
    {
        const int nw4 = nwords >> 2;
        const uint4* s4 = reinterpret_cast<const uint4*>(packedT);
        uint4* d4 = reinterpret_cast<uint4*>(typeT);
        for (int i = t; i < nw4; i += THREADS) d4[i] = s4[i];
        for (int i = (nw4 << 2) + t; i < nwords; i += THREADS) typeT[i] = packedT[i];
    }
    __syncthreads();

    #define TYPE_OF(idx) ((typeT[(idx) >> 3] >> (((idx) & 7) << 2)) & 15u)

    const int blk     = blockIdx.x;
    const int rep8    = blk & (NREP - 1);
    const int blkbase = blk * EPB;
    const int nval    = min(EPB, n_edges - blkbase);

    // 8 edges/thread: lookup + energy + pack + histogram
    uint32_t pk[EPT];
    int      bk[EPT];
    #pragma unroll
    for (int i = 0; i < EPT / 4; ++i) {
        const int g = blkbase + i * (THREADS * 4) + t * 4;
        if (g + 3 < n_edges) {
            const int4   ctr = *reinterpret_cast<const int4*>(edge_index + g);
            const int4   oth = *reinterpret_cast<const int4*>(edge_index + n_edges + g);
            const float4 len = *reinterpret_cast<const float4*>(edge_len + g);
            const float4 cut = *reinterpret_cast<const float4*>(edge_cutoff + g);
            const int   c[4] = {ctr.x, ctr.y, ctr.z, ctr.w};
            const int   o[4] = {oth.x, oth.y, oth.z, oth.w};
            const float L[4] = {len.x, len.y, len.z, len.w};
            const float C[4] = {cut.x, cut.y, cut.z, cut.w};
            #pragma unroll
            for (int k = 0; k < 4; ++k) {
                const int fl = (int)((TYPE_OF(c[k]) << 4) | TYPE_OF(o[k]));
                const float e = lj_energy(s_sig[fl], s_dlt[fl], s_eps[fl], L[k], C[k]);
                pk[i*4+k] = (__float_as_uint(e) & ~NMASK) | (uint32_t)(c[k] & NMASK);
                bk[i*4+k] = c[k] >> BSHIFT;
                atomicAdd(&hist[bk[i*4+k]], 1u);
            }
        } else {
            #pragma unroll
            for (int k = 0; k < 4; ++k) {
                const int e_idx = g + k;
                if (e_idx < n_edges) {
                    const int ci = edge_index[e_idx];
                    const int oi = edge_index[n_edges + e_idx];
                    const int fl = (int)((TYPE_OF(ci) << 4) | TYPE_OF(oi));
                    const float e = lj_energy(s_sig[fl], s_dlt[fl], s_eps[fl],
                                              edge_len[e_idx], edge_cutoff[e_idx]);
                    pk[i*4+k] = (__float_as_uint(e) & ~NMASK) | (uint32_t)(ci & NMASK);
                    bk[i*4+k] = ci >> BSHIFT;
                    atomicAdd(&hist[bk[i*4+k]], 1u);
                } else {
                    bk[i*4+k] = -1;
                }
            }
        }
    }
    __syncthreads();

    // wave-0 in-register exclusive scan of hist[0..255] (4 entries/lane)
    if (t < 64) {
        uint32_t v[4]; uint32_t s = 0;
        #pragma unroll
        for (int k = 0; k < 4; ++k) {
            const uint32_t tmp = hist[t * 4 + k];
            v[k] = s; s += tmp;
        }
        uint32_t inc = s;
        #pragma unroll
        for (int off = 1; off < 64; off <<= 1) {
            const uint32_t u = __shfl_up(inc, off, 64);
            if (t >= off) inc += u;
        }
        const uint32_t lane_excl = inc - s;
        #pragma unroll
        for (int k = 0; k < 4; ++k) {
            const uint32_t e = lane_excl + v[k];
            lbase[t * 4 + k] = e;
            hist[t * 4 + k]  = e;        // cursor
        }
    }
    __syncthreads();

    // reserve region slots in replica rep8: u64 bucket-pair atomics, depth ~nblk/8
    if (t < MAXB2 / 2) {
        const int b0 = 2 * t, b1 = 2 * t + 1;
        const uint32_t l0 = lbase[b0];
        const uint32_t l1 = lbase[b1];
        const uint32_t l2 = (b1 + 1 < MAXB2) ? lbase[b1 + 1] : (uint32_t)nval;
        const uint32_t cnt0 = l1 - l0;
        const uint32_t cnt1 = l2 - l1;
        if ((cnt0 | cnt1) != 0u) {
            unsigned long long* g64 =
                reinterpret_cast<unsigned long long*>(gcursor + rep8 * 256) + t;
            const unsigned long long add =
                (unsigned long long)cnt0 | ((unsigned long long)cnt1 << 32);
            const unsigned long long old = atomicAdd(g64, add);
            gbase[b0] = (uint32_t)old;
            gbase[b1] = (uint32_t)(old >> 32);
        }
    }
    // rank-scatter into the LDS stage (overlaps the reservation latency)
    #pragma unroll
    for (int j = 0; j < EPT; ++j) {
        if (bk[j] >= 0) {
            const uint32_t r = atomicAdd(&hist[bk[j]], 1u);
            stage[r] = pk[j];
        }
    }
    __syncthreads();

    // run-coalesced copy-out into this block's replica sub-chunk
    const int grp = t >> 3;              // 64 groups of 8 lanes
    const int lig = t & 7;
    for (int b = grp; b < nbucket; b += 64) {
        const uint32_t l0 = lbase[b];
        const uint32_t l1 = (b + 1 < MAXB2) ? lbase[b + 1] : (uint32_t)nval;
        const uint32_t cnt = l1 - l0;
        const uint32_t base = gbase[b];
        const uint32_t avail = (base < (uint32_t)REGr)
                             ? min(cnt, (uint32_t)REGr - base) : 0u;  // overflow guard
        uint32_t* dst = pairs + ((size_t)b * NREP + rep8) * REGr + base;
        for (uint32_t j = lig; j < avail; j += 8)
            dst[j] = stage[l0 + j];
    }
}

// ---------------- K2: per-bucket accumulate -> out (wave per replica-chunk) ---
__global__ __launch_bounds__(THREADS) void lj_accum_direct(
    const uint32_t* __restrict__ pairs,
    const uint32_t* __restrict__ gcursor,
    float* __restrict__ out,
    int REGr, int n_nodes)
{
    __shared__ float acc[4][BSIZE];          // 8KB, 4 replicas
    const int t = threadIdx.x;
    const int b = blockIdx.x;

    #pragma unroll
    for (int w = 0; w < 4; ++w) acc[w][t] = 0.0f;
    __syncthreads();

    const int wave = t >> 6;                 // 0..7: one wave per replica chunk
    const int lane = t & 63;
    const uint32_t cnt = min(gcursor[wave * 256 + b], (uint32_t)REGr);
    const uint32_t* seg = pairs + ((size_t)b * NREP + wave) * REGr;
    const int ar = wave & 3;
    for (uint32_t i = lane; i < cnt; i += 64) {
        const uint32_t p = seg[i];
        atomicAdd(&acc[ar][p & NMASK], __uint_as_float(p & ~NMASK));
    }
    __syncthreads();

    const long long n = (long long)b * BSIZE + t;
    if (n < n_nodes)
        out[n] = acc[0][t] + acc[1][t] + acc[2][t] + acc[3][t];
}

// ---------------- fallback: direct device-scope atomics -----------------------
__global__ __launch_bounds__(STHREADS) void lj_scatter_direct(
    const float* __restrict__ sigma,
    const float* __restrict__ delta,
    const float* __restrict__ epsilon,
    const float* __restrict__ edge_len,
    const float* __restrict__ edge_cutoff,
    const int*  __restrict__ edge_index,
    const int*  __restrict__ atom_types,
    float* __restrict__ out,
    int n_edges)
{
    __shared__ float s_sig[256], s_dlt[256], s_eps[256];
    const int t = threadIdx.x;
    load_params(sigma, delta, epsilon, s_sig, s_dlt, s_eps, t);
    __syncthreads();

    const int base = (blockIdx.x * STHREADS + t) * 4;
    if (base >= n_edges) return;
    const int lim = min(base + 4, n_edges);
    for (int e = base; e < lim; ++e) {
        const int ci = edge_index[e];
        const int oi = edge_index[n_edges + e];
        const int fl = (atom_types[ci] << 4) | atom_types[oi];
        const float en = lj_energy(s_sig[fl], s_dlt[fl], s_eps[fl],
                                   edge_len[e], edge_cutoff[e]);
        atomicAdd(out + ci, en);
    }
}

static inline size_t align16(size_t x) { return (x + 15) & ~(size_t)15; }

extern "C" void kernel_launch(void* const* d_in, const int* in_sizes, int n_in,
                              void* d_out, int out_size, void* d_ws, size_t ws_size,
                              hipStream_t stream) {
    const float* sigma       = (const float*)d_in[0];
    const float* delta       = (const float*)d_in[1];
    const float* epsilon     = (const float*)d_in[2];
    const float* edge_len    = (const float*)d_in[3];
    const float* edge_cutoff = (const float*)d_in[4];
    const int*   edge_index  = (const int*)d_in[5];
    const int*   atom_types  = (const int*)d_in[6];
    float*       out         = (float*)d_out;

    const int n_edges = in_sizes[3];
    const int n_nodes = in_sizes[6];

    const int nblk    = (n_edges + EPB - 1) / EPB;
    const int nbucket = (n_nodes + BSIZE - 1) / BSIZE;
    const int nwords  = (n_nodes + 7) >> 3;

    // per-(bucket,replica) sub-chunk: 2x mean, rounded to 512 (>=1024)
    int REGr = 2 * (n_edges / (nbucket > 0 ? nbucket * NREP : NREP));
    REGr = ((REGr + 511) / 512) * 512;
    if (REGr < 1024) REGr = 1024;

    const size_t gcur_bytes   = align16((size_t)NREP * 256 * sizeof(uint32_t));
    const size_t packed_bytes = align16((size_t)nwords * sizeof(uint32_t));
    const size_t pairs_bytes  = align16((size_t)nbucket * NREP * REGr * sizeof(uint32_t));
    const size_t need = gcur_bytes + packed_bytes + pairs_bytes;

    if (nbucket <= MAXB2 && nwords <= LDSWORDS && ws_size >= need) {
        char* p = (char*)d_ws;
        uint32_t* gcursor = (uint32_t*)p;  p += gcur_bytes;
        uint32_t* packed  = (uint32_t*)p;  p += packed_bytes;
        uint32_t* pairs   = (uint32_t*)p;

        const int pgrid = max((nwords + STHREADS - 1) / STHREADS, NREP);
        pack_types_kernel<<<pgrid, STHREADS, 0, stream>>>(
            atom_types, packed, gcursor, n_nodes);

        lj_fused<<<nblk, THREADS, 0, stream>>>(
            sigma, delta, epsilon, edge_len, edge_cutoff,
            edge_index, packed, gcursor, pairs, n_edges, n_nodes, nbucket, REGr);

        lj_accum_direct<<<nbucket, THREADS, 0, stream>>>(
            pairs, gcursor, out, REGr, n_nodes);
    } else {
        hipMemsetAsync(d_out, 0, (size_t)out_size * sizeof(float), stream);
        const int grid = (n_edges + STHREADS * 4 - 1) / (STHREADS * 4);
        lj_scatter_direct<<<grid, STHREADS, 0, stream>>>(
            sigma, delta, epsilon, edge_len, edge_cutoff,
            edge_index, atom_types, out, n_edges);
    }
}